// Round 9
// baseline (987.355 us; speedup 1.0000x reference)
//
#include <hip/hip_runtime.h>

#define N_NODES 100000
#define N_EDGES 1600000
#define NFEAT 256
#define NHID 64
#define NOUT 16
#define BSIZE 128            // dst-nodes per bucket
#define NBUCK 782            // ceil(N_NODES/128)
#define CHUNK 8192           // edges per chunk
#define NCHUNK 196           // ceil(N_EDGES/8192)
#define MATN (NBUCK * NCHUNK)   // 153,272
#define MSCAN_NB 599         // ceil(MATN/256)

__device__ __forceinline__ unsigned short f2bf(float f) {
  unsigned u = __float_as_uint(f);
  unsigned r = (u + 0x7FFF + ((u >> 16) & 1)) >> 16;  // RNE
  return (unsigned short)r;
}
__device__ __forceinline__ float bf2f(unsigned short b) {
  return __uint_as_float(((unsigned)b) << 16);
}

// ---------------------------------------------------------------------------
// S1: per-chunk bucket histogram -> histMat[bucket*NCHUNK + chunk]
// ---------------------------------------------------------------------------
__global__ __launch_bounds__(256) void histB_kernel(
    const int* __restrict__ dst, int* __restrict__ histMat) {
  __shared__ int hist[NBUCK];
  int t = threadIdx.x;
  int ch = blockIdx.x;
  for (int i = t; i < NBUCK; i += 256) hist[i] = 0;
  __syncthreads();
  int base = ch * CHUNK;
#pragma unroll
  for (int i = 0; i < CHUNK / 256; ++i) {
    int e = base + i * 256 + t;
    if (e < N_EDGES) atomicAdd(&hist[dst[e] >> 7], 1);
  }
  __syncthreads();
  for (int i = t; i < NBUCK; i += 256) histMat[i * NCHUNK + ch] = hist[i];
}

// ---------------------------------------------------------------------------
// S2a: per-256-block scan of histMat -> exclusive-within-block + blockSums
// ---------------------------------------------------------------------------
__global__ __launch_bounds__(256) void mscan1_kernel(
    const int* __restrict__ histMat, int* __restrict__ scanTmp,
    int* __restrict__ blockSums) {
  __shared__ int s[256];
  int t = threadIdx.x;
  int i = blockIdx.x * 256 + t;
  int v = (i < MATN) ? histMat[i] : 0;
  s[t] = v;
  __syncthreads();
  for (int off = 1; off < 256; off <<= 1) {
    int x = (t >= off) ? s[t - off] : 0;
    __syncthreads();
    s[t] += x;
    __syncthreads();
  }
  if (i < MATN) scanTmp[i] = s[t] - v;  // exclusive within block
  if (t == 255) blockSums[blockIdx.x] = s[255];
}

// ---------------------------------------------------------------------------
// S2b: single-block exclusive scan of MSCAN_NB block sums (<=1024)
// ---------------------------------------------------------------------------
__global__ __launch_bounds__(1024) void mscan2_kernel(
    const int* __restrict__ blockSums, int* __restrict__ blockOff) {
  __shared__ int s[1024];
  int t = threadIdx.x;
  int v = (t < MSCAN_NB) ? blockSums[t] : 0;
  s[t] = v;
  __syncthreads();
  for (int off = 1; off < 1024; off <<= 1) {
    int x = (t >= off) ? s[t - off] : 0;
    __syncthreads();
    s[t] += x;
    __syncthreads();
  }
  if (t < MSCAN_NB) blockOff[t] = s[t] - v;  // exclusive
}

// ---------------------------------------------------------------------------
// S2c: mEx[i] = scanTmp[i] + blockOff[block]   (in-place over histMat)
// ---------------------------------------------------------------------------
__global__ __launch_bounds__(256) void mscan3_kernel(
    const int* __restrict__ scanTmp, const int* __restrict__ blockOff,
    int* __restrict__ mEx) {
  int i = blockIdx.x * 256 + threadIdx.x;
  if (i < MATN) mEx[i] = scanTmp[i] + blockOff[blockIdx.x];
}

// ---------------------------------------------------------------------------
// S3: scatter edges into bucket-grouped tmp_vs. No global atomics: each
// (bucket,chunk) range is exclusively owned by this block (from mEx).
// dlow = dst&127 packed into bits 17..23 of x (src < 2^17).
// ---------------------------------------------------------------------------
__global__ __launch_bounds__(256) void scatter2_kernel(
    const int* __restrict__ src, const int* __restrict__ dst,
    const float* __restrict__ edge_val, const int* __restrict__ mEx,
    int2* __restrict__ tmp_vs) {
  __shared__ int cur[NBUCK];
  int t = threadIdx.x;
  int bid = blockIdx.x;
  // bijective XCD swizzle over NCHUNK chunks
  int xcd = bid & 7;
  int q = NCHUNK >> 3, r = NCHUNK & 7;
  int ch = (xcd < r ? xcd * (q + 1) : r * (q + 1) + (xcd - r) * q) + (bid >> 3);
  for (int i = t; i < NBUCK; i += 256) cur[i] = mEx[i * NCHUNK + ch];
  __syncthreads();
  int base = ch * CHUNK;
#pragma unroll
  for (int i = 0; i < CHUNK / 256; ++i) {
    int e = base + i * 256 + t;
    if (e < N_EDGES) {
      int d = dst[e];
      int p = atomicAdd(&cur[d >> 7], 1);  // LDS atomic
      int2 vs;
      vs.x = src[e] | ((d & 127) << 17);
      vs.y = __float_as_int(edge_val[e]);
      tmp_vs[p] = vs;
    }
  }
}

// ---------------------------------------------------------------------------
// S4: within-bucket counting sort by SRC-GRANULE (src>>9, 512-node granules).
// Makes each spmm block's gather stream ascend through support1/support2 ->
// sequential beyond-L2 fetches + cross-block temporal L2 alignment.
// Keeps dlow packed in bits 17..23 for the LDS-accumulate spmm kernels.
// ---------------------------------------------------------------------------
__global__ __launch_bounds__(256) void bucket_sort_kernel(
    const int2* __restrict__ tmp_vs, const int* __restrict__ mEx,
    int2* __restrict__ sorted_vs) {
  __shared__ int cnt[256], scn[256], cur[256];
  int b = blockIdx.x;
  int t = threadIdx.x;
  int bstart = mEx[b * NCHUNK];
  int bend = (b + 1 < NBUCK) ? mEx[(b + 1) * NCHUNK] : N_EDGES;
  cnt[t] = 0;
  __syncthreads();
  for (int e = bstart + t; e < bend; e += 256)
    atomicAdd(&cnt[(tmp_vs[e].x & 0x1FFFF) >> 9], 1);
  __syncthreads();
  scn[t] = cnt[t];
  __syncthreads();
  for (int off = 1; off < 256; off <<= 1) {
    int x = (t >= off) ? scn[t - off] : 0;
    __syncthreads();
    scn[t] += x;
    __syncthreads();
  }
  cur[t] = bstart + scn[t] - cnt[t];
  __syncthreads();
  for (int e = bstart + t; e < bend; e += 256) {
    int2 vs = tmp_vs[e];
    int key = (vs.x & 0x1FFFF) >> 9;
    int p = atomicAdd(&cur[key], 1);
    sorted_vs[p] = vs;  // keep dlow bits
  }
}

// ---------------------------------------------------------------------------
// K1: support1 = bf16(emb @ W1)   [100000,256] @ [256,64]
// Block = 64 rows x 4 waves; wave wq owns col-quarter [wq*16, wq*16+16).
// ---------------------------------------------------------------------------
__global__ __launch_bounds__(256) void gemm1_kernel(
    const float* __restrict__ emb, const float* __restrict__ W1,
    unsigned short* __restrict__ out) {
  int lane = threadIdx.x & 63;
  int wq = __builtin_amdgcn_readfirstlane(threadIdx.x >> 6);
  int row = blockIdx.x * 64 + lane;
  int rclamp = row < N_NODES ? row : (N_NODES - 1);
  const float* er = emb + (size_t)rclamp * NFEAT;
  const float* w1q = W1 + wq * 16;  // scalar base

  float acc[16];
#pragma unroll
  for (int c = 0; c < 16; ++c) acc[c] = 0.f;

  for (int k0 = 0; k0 < NFEAT; k0 += 16) {
    float eb[16];
#pragma unroll
    for (int q = 0; q < 4; ++q)
      *(float4*)(eb + 4 * q) = *(const float4*)(er + k0 + 4 * q);
#pragma unroll
    for (int j = 0; j < 16; ++j) {
      const float* w = w1q + (size_t)(k0 + j) * NHID;  // lane-invariant
#pragma unroll
      for (int c = 0; c < 16; ++c) acc[c] = fmaf(eb[j], w[c], acc[c]);
    }
  }

  if (row < N_NODES) {
    unsigned short* o = out + (size_t)row * NHID + wq * 16;
    ushort4 pk[4];
#pragma unroll
    for (int g = 0; g < 4; ++g) {
      pk[g].x = f2bf(acc[4 * g + 0]);
      pk[g].y = f2bf(acc[4 * g + 1]);
      pk[g].z = f2bf(acc[4 * g + 2]);
      pk[g].w = f2bf(acc[4 * g + 3]);
    }
    *(ushort4*)(o + 0) = pk[0];
    *(ushort4*)(o + 4) = pk[1];
    *(ushort4*)(o + 8) = pk[2];
    *(ushort4*)(o + 12) = pk[3];
  }
}

// ---------------------------------------------------------------------------
// K2: bucket-accumulate spmm1 + fused bias/relu/dropout/W2.
// Block = 1 bucket (128 dst rows), LDS hacc[128][64] f32 (32 KB).
// Edges ascend in src -> sequential support1 stream. ds_add_f32 accumulate
// (lane l -> bank l%32, 2-way aliasing = free).
// ---------------------------------------------------------------------------
__global__ __launch_bounds__(256) void spmm1_fused_kernel(
    const unsigned short* __restrict__ support1,
    const int2* __restrict__ sorted_vs, const int* __restrict__ mEx,
    const float* __restrict__ b1, const float* __restrict__ mask,
    const float* __restrict__ W2, float* __restrict__ support2) {
  __shared__ float hacc[BSIZE][NHID];  // 32 KB
  int b = blockIdx.x;
  int t = threadIdx.x;
  int lane = t & 63;
  int wv = t >> 6;  // 0..3
  for (int i = t; i < BSIZE * NHID; i += 256) ((float*)hacc)[i] = 0.f;
  __syncthreads();
  int bstart = mEx[b * NCHUNK];
  int bend = (b + 1 < NBUCK) ? mEx[(b + 1) * NCHUNK] : N_EDGES;
#pragma unroll 4
  for (int e = bstart + wv; e < bend; e += 4) {
    int2 vs = sorted_vs[e];
    int s = vs.x & 0x1FFFF;
    int dl = (vs.x >> 17) & 127;
    float x = bf2f(support1[(size_t)s * NHID + lane]);
    atomicAdd(&hacc[dl][lane], __int_as_float(vs.y) * x);
  }
  __syncthreads();
  // epilogue phase 1: h = relu(hacc + b1) * mask (in place)
  int node0 = b * BSIZE;
  for (int rl = wv; rl < BSIZE; rl += 4) {
    int node = node0 + rl;
    if (node < N_NODES) {
      float h = fmaxf(hacc[rl][lane] + b1[lane], 0.f) *
                mask[(size_t)node * NHID + lane];
      hacc[rl][lane] = h;
    }
  }
  __syncthreads();
  // epilogue phase 2: support2[node] = h @ W2 (16-lane groups + shfl reduce)
  int q = lane >> 4, c = lane & 15;
  for (int rl = wv; rl < BSIZE; rl += 4) {
    int node = node0 + rl;
    if (node < N_NODES) {
      float p = 0.f;
#pragma unroll
      for (int i = 0; i < 16; ++i) {
        int k = q * 16 + i;
        p = fmaf(hacc[rl][k], W2[k * NOUT + c], p);
      }
      p += __shfl_xor(p, 16);
      p += __shfl_xor(p, 32);
      if (lane < 16) support2[(size_t)node * NOUT + lane] = p;
    }
  }
}

// ---------------------------------------------------------------------------
// K3: bucket-accumulate spmm2 + b2. LDS oacc[128][16] f32 (8 KB).
// 16 lanes per edge, 16 edge-slots per block-iteration.
// ---------------------------------------------------------------------------
__global__ __launch_bounds__(256) void spmm2_acc_kernel(
    const float* __restrict__ support2, const int2* __restrict__ sorted_vs,
    const int* __restrict__ mEx, const float* __restrict__ b2,
    float* __restrict__ out) {
  __shared__ float oacc[BSIZE][NOUT];  // 8 KB
  int b = blockIdx.x;
  int t = threadIdx.x;
  int c = t & 15;
  int slot = t >> 4;  // 0..15
  for (int i = t; i < BSIZE * NOUT; i += 256) ((float*)oacc)[i] = 0.f;
  __syncthreads();
  int bstart = mEx[b * NCHUNK];
  int bend = (b + 1 < NBUCK) ? mEx[(b + 1) * NCHUNK] : N_EDGES;
#pragma unroll 4
  for (int e = bstart + slot; e < bend; e += 16) {
    int2 vs = sorted_vs[e];
    int s = vs.x & 0x1FFFF;
    int dl = (vs.x >> 17) & 127;
    atomicAdd(&oacc[dl][c],
              __int_as_float(vs.y) * support2[(size_t)s * NOUT + c]);
  }
  __syncthreads();
  int node0 = b * BSIZE;
  for (int rl = slot; rl < BSIZE; rl += 16) {
    int node = node0 + rl;
    if (node < N_NODES) out[(size_t)node * NOUT + c] = oacc[rl][c] + b2[c];
  }
}

extern "C" void kernel_launch(void* const* d_in, const int* in_sizes, int n_in,
                              void* d_out, int out_size, void* d_ws,
                              size_t ws_size, hipStream_t stream) {
  const float* emb = (const float*)d_in[0];
  const float* W1 = (const float*)d_in[1];
  const float* b1 = (const float*)d_in[2];
  const float* W2 = (const float*)d_in[3];
  const float* b2 = (const float*)d_in[4];
  const float* edge_val = (const float*)d_in[5];
  const float* mask = (const float*)d_in[6];
  const int* esrc = (const int*)d_in[7];
  const int* edst = (const int*)d_in[8];

  // workspace layout (4-byte units)
  float* ws = (float*)d_ws;
  int2* tmp_vs = (int2*)ws;                           // 1.6M int2 (12.8 MB)
  unsigned short* support1 = (unsigned short*)ws;     // aliases tmp_vs
                                                      //  (written after sort)
  int2* sorted_vs = (int2*)(ws + 6400000);            // 1.6M int2
  float* support2 = ws + 9600000;                     // 1.6M f
  int* scanTmpM = (int*)support2;                     // aliases support2 (dead
                                                      //  before spmm1 writes)
  int* histMat = (int*)(ws + 11200000);               // 153,272 i (becomes mEx)
  int* mBlockSums = histMat + MATN;                   // 1024 i
  int* mBlockOff = mBlockSums + 1024;                 // 1024 i
  float* out = (float*)d_out;

  // CSR-bucket build: chunk-histogram -> matrix scan -> ownership scatter
  // -> within-bucket src-granule sort
  histB_kernel<<<NCHUNK, 256, 0, stream>>>(edst, histMat);
  mscan1_kernel<<<MSCAN_NB, 256, 0, stream>>>(histMat, scanTmpM, mBlockSums);
  mscan2_kernel<<<1, 1024, 0, stream>>>(mBlockSums, mBlockOff);
  mscan3_kernel<<<MSCAN_NB, 256, 0, stream>>>(scanTmpM, mBlockOff, histMat);
  scatter2_kernel<<<NCHUNK, 256, 0, stream>>>(esrc, edst, edge_val, histMat,
                                              tmp_vs);
  bucket_sort_kernel<<<NBUCK, 256, 0, stream>>>(tmp_vs, histMat, sorted_vs);

  // dense + sparse pipeline (gemm1 after sort: support1 aliases tmp_vs)
  gemm1_kernel<<<(N_NODES + 63) / 64, 256, 0, stream>>>(emb, W1, support1);
  spmm1_fused_kernel<<<NBUCK, 256, 0, stream>>>(support1, sorted_vs, histMat,
                                                b1, mask, W2, support2);
  spmm2_acc_kernel<<<NBUCK, 256, 0, stream>>>(support2, sorted_vs, histMat,
                                              b2, out);
}

// Round 11
// 269.272 us; speedup vs baseline: 3.6668x; 3.6668x over previous
//
#include <hip/hip_runtime.h>

#define N_NODES 100000
#define N_EDGES 1600000
#define NFEAT 256
#define NHID 64
#define NOUT 16
#define BSIZE 256            // dst-nodes per bucket
#define NBUCK 391            // ceil(N_NODES/256)
#define CHUNK 4096           // edges per chunk
#define NCHUNK 391           // ceil(N_EDGES/4096)
#define MATN (NBUCK * NCHUNK)
#define MSCAN_NB 598         // ceil(MATN/256)

__device__ __forceinline__ unsigned short f2bf(float f) {
  unsigned u = __float_as_uint(f);
  unsigned r = (u + 0x7FFF + ((u >> 16) & 1)) >> 16;  // RNE
  return (unsigned short)r;
}
__device__ __forceinline__ float bf2f(unsigned short b) {
  return __uint_as_float(((unsigned)b) << 16);
}

// ---------------------------------------------------------------------------
// S1: per-chunk bucket histogram -> histMat[bucket*NCHUNK + chunk]
// ---------------------------------------------------------------------------
__global__ __launch_bounds__(256) void histB_kernel(
    const int* __restrict__ dst, int* __restrict__ histMat) {
  __shared__ int hist[NBUCK];
  int t = threadIdx.x;
  int ch = blockIdx.x;
  if (t < NBUCK) hist[t] = 0;
  if (t + 256 < NBUCK) hist[t + 256] = 0;
  __syncthreads();
  int base = ch * CHUNK;
#pragma unroll
  for (int i = 0; i < CHUNK / 256; ++i) {
    int e = base + i * 256 + t;
    if (e < N_EDGES) atomicAdd(&hist[dst[e] >> 8], 1);
  }
  __syncthreads();
  if (t < NBUCK) histMat[t * NCHUNK + ch] = hist[t];
  if (t + 256 < NBUCK) histMat[(t + 256) * NCHUNK + ch] = hist[t + 256];
}

// ---------------------------------------------------------------------------
// S2a: per-256-block scan of histMat -> exclusive-within-block + blockSums
// ---------------------------------------------------------------------------
__global__ __launch_bounds__(256) void mscan1_kernel(
    const int* __restrict__ histMat, int* __restrict__ scanTmp,
    int* __restrict__ blockSums) {
  __shared__ int s[256];
  int t = threadIdx.x;
  int i = blockIdx.x * 256 + t;
  int v = (i < MATN) ? histMat[i] : 0;
  s[t] = v;
  __syncthreads();
  for (int off = 1; off < 256; off <<= 1) {
    int x = (t >= off) ? s[t - off] : 0;
    __syncthreads();
    s[t] += x;
    __syncthreads();
  }
  if (i < MATN) scanTmp[i] = s[t] - v;  // exclusive within block
  if (t == 255) blockSums[blockIdx.x] = s[255];
}

// ---------------------------------------------------------------------------
// S2b: single-block exclusive scan of MSCAN_NB block sums (<=1024)
// ---------------------------------------------------------------------------
__global__ __launch_bounds__(1024) void mscan2_kernel(
    const int* __restrict__ blockSums, int* __restrict__ blockOff) {
  __shared__ int s[1024];
  int t = threadIdx.x;
  int v = (t < MSCAN_NB) ? blockSums[t] : 0;
  s[t] = v;
  __syncthreads();
  for (int off = 1; off < 1024; off <<= 1) {
    int x = (t >= off) ? s[t - off] : 0;
    __syncthreads();
    s[t] += x;
    __syncthreads();
  }
  if (t < MSCAN_NB) blockOff[t] = s[t] - v;  // exclusive
}

// ---------------------------------------------------------------------------
// S2c: mEx[i] = scanTmp[i] + blockOff[block]   (in-place over histMat)
// ---------------------------------------------------------------------------
__global__ __launch_bounds__(256) void mscan3_kernel(
    const int* __restrict__ scanTmp, const int* __restrict__ blockOff,
    int* __restrict__ mEx) {
  int i = blockIdx.x * 256 + threadIdx.x;
  if (i < MATN) mEx[i] = scanTmp[i] + blockOff[blockIdx.x];
}

// ---------------------------------------------------------------------------
// S3: scatter edges into bucket-grouped tmp_vs. No global atomics: each
// (bucket,chunk) range is exclusively owned by this block (from mEx).
// dlow = dst&255 packed into bits 17..24 of x (src < 2^17).
// ---------------------------------------------------------------------------
__global__ __launch_bounds__(256) void scatter2_kernel(
    const int* __restrict__ src, const int* __restrict__ dst,
    const float* __restrict__ edge_val, const int* __restrict__ mEx,
    int2* __restrict__ tmp_vs) {
  __shared__ int cur[NBUCK];
  int t = threadIdx.x;
  int bid = blockIdx.x;
  // bijective XCD swizzle: q=NCHUNK/8, r=NCHUNK%8
  int xcd = bid & 7;
  int q = NCHUNK >> 3, r = NCHUNK & 7;
  int ch = (xcd < r ? xcd * (q + 1) : r * (q + 1) + (xcd - r) * q) + (bid >> 3);
  if (t < NBUCK) cur[t] = mEx[t * NCHUNK + ch];
  if (t + 256 < NBUCK) cur[t + 256] = mEx[(t + 256) * NCHUNK + ch];
  __syncthreads();
  int base = ch * CHUNK;
#pragma unroll
  for (int i = 0; i < CHUNK / 256; ++i) {
    int e = base + i * 256 + t;
    if (e < N_EDGES) {
      int d = dst[e];
      int p = atomicAdd(&cur[d >> 8], 1);  // LDS atomic
      int2 vs;
      vs.x = src[e] | ((d & 255) << 17);
      vs.y = __float_as_int(edge_val[e]);
      tmp_vs[p] = vs;
    }
  }
}

// ---------------------------------------------------------------------------
// S4: within-bucket counting sort. One block per bucket (256 nodes):
// pass1 counts nodes in LDS, local scan -> row_start/counts written here,
// pass2 scatters into exact CSR slots (~32 KB L2-resident window).
// ---------------------------------------------------------------------------
__global__ __launch_bounds__(256) void bucket_sort_kernel(
    const int2* __restrict__ tmp_vs, const int* __restrict__ mEx,
    int2* __restrict__ sorted_vs, int* __restrict__ row_start,
    int* __restrict__ counts) {
  __shared__ int cnt[256], scn[256], cur[256];
  int b = blockIdx.x;
  int t = threadIdx.x;
  int bstart = mEx[b * NCHUNK];
  int bend = (b + 1 < NBUCK) ? mEx[(b + 1) * NCHUNK] : N_EDGES;
  cnt[t] = 0;
  __syncthreads();
  for (int e = bstart + t; e < bend; e += 256)
    atomicAdd(&cnt[((unsigned)tmp_vs[e].x) >> 17], 1);
  __syncthreads();
  scn[t] = cnt[t];
  __syncthreads();
  for (int off = 1; off < 256; off <<= 1) {
    int x = (t >= off) ? scn[t - off] : 0;
    __syncthreads();
    scn[t] += x;
    __syncthreads();
  }
  int excl = scn[t] - cnt[t];
  cur[t] = bstart + excl;
  int node = (b << 8) + t;
  if (node < N_NODES) {
    row_start[node] = bstart + excl;
    counts[node] = cnt[t];
  }
  __syncthreads();
  for (int e = bstart + t; e < bend; e += 256) {
    int2 vs = tmp_vs[e];
    int dlow = ((unsigned)vs.x) >> 17;
    int p = atomicAdd(&cur[dlow], 1);
    int2 o;
    o.x = vs.x & 0x1FFFF;
    o.y = vs.y;
    sorted_vs[p] = o;
  }
}

// ---------------------------------------------------------------------------
// K1: support1 = bf16(emb @ W1)   [100000,256] @ [256,64]
// Block = 64 rows x 4 waves; wave wq owns col-quarter [wq*16, wq*16+16).
// ---------------------------------------------------------------------------
__global__ __launch_bounds__(256) void gemm1_kernel(
    const float* __restrict__ emb, const float* __restrict__ W1,
    unsigned short* __restrict__ out) {
  int lane = threadIdx.x & 63;
  int wq = __builtin_amdgcn_readfirstlane(threadIdx.x >> 6);
  int row = blockIdx.x * 64 + lane;
  int rclamp = row < N_NODES ? row : (N_NODES - 1);
  const float* er = emb + (size_t)rclamp * NFEAT;
  const float* w1q = W1 + wq * 16;  // scalar base

  float acc[16];
#pragma unroll
  for (int c = 0; c < 16; ++c) acc[c] = 0.f;

  for (int k0 = 0; k0 < NFEAT; k0 += 16) {
    float eb[16];
#pragma unroll
    for (int q = 0; q < 4; ++q)
      *(float4*)(eb + 4 * q) = *(const float4*)(er + k0 + 4 * q);
#pragma unroll
    for (int j = 0; j < 16; ++j) {
      const float* w = w1q + (size_t)(k0 + j) * NHID;  // lane-invariant
#pragma unroll
      for (int c = 0; c < 16; ++c) acc[c] = fmaf(eb[j], w[c], acc[c]);
    }
  }

  if (row < N_NODES) {
    unsigned short* o = out + (size_t)row * NHID + wq * 16;
    ushort4 pk[4];
#pragma unroll
    for (int g = 0; g < 4; ++g) {
      pk[g].x = f2bf(acc[4 * g + 0]);
      pk[g].y = f2bf(acc[4 * g + 1]);
      pk[g].z = f2bf(acc[4 * g + 2]);
      pk[g].w = f2bf(acc[4 * g + 3]);
    }
    *(ushort4*)(o + 0) = pk[0];
    *(ushort4*)(o + 4) = pk[1];
    *(ushort4*)(o + 8) = pk[2];
    *(ushort4*)(o + 12) = pk[3];
  }
}

// ---------------------------------------------------------------------------
// K2 (fused): wave per dst row, latency-optimized.
// Cooperative edge prefetch: lane i holds edge (beg+i) -> ONE coalesced load
// per 64 edges; shfl broadcast (uniform loop: all lanes iterate i=0..n-1 in
// lockstep, so every __shfl runs with full EXEC) feeds independent gathers.
//   acc[lane] = sum_e val_e * bf16 support1[src_e][lane]
//   h = relu(acc + b1) * mask ;  support2 = h @ W2 (LDS + shfl reduce)
// ---------------------------------------------------------------------------
__global__ __launch_bounds__(256) void spmm1_fused_kernel(
    const unsigned short* __restrict__ support1,
    const int2* __restrict__ sorted_vs, const int* __restrict__ row_start,
    const int* __restrict__ counts, const float* __restrict__ b1,
    const float* __restrict__ mask, const float* __restrict__ W2,
    float* __restrict__ support2) {
  int wave = (blockIdx.x * blockDim.x + threadIdx.x) >> 6;
  int lane = threadIdx.x & 63;
  int wib = threadIdx.x >> 6;
  int r = wave;
  int beg = row_start[r];
  int cnt = counts[r];
  float acc = 0.f;
  for (int b64 = 0; b64 < cnt; b64 += 64) {
    int n = min(64, cnt - b64);
    int2 myvs;
    myvs.x = 0;
    myvs.y = 0;
    if (lane < n) myvs = sorted_vs[beg + b64 + lane];
#pragma unroll 4
    for (int i = 0; i < n; ++i) {  // uniform trip count: full EXEC at shfl
      int sx = __shfl(myvs.x, i);
      float v = __int_as_float(__shfl(myvs.y, i));
      acc = fmaf(v, bf2f(support1[(size_t)sx * NHID + lane]), acc);
    }
  }
  float h = fmaxf(acc + b1[lane], 0.f) * mask[(size_t)r * NHID + lane];

  __shared__ float hsh[4][NHID];
  hsh[wib][lane] = h;
  __syncthreads();
  int q = lane >> 4;   // 0..3 : k-quarter
  int c = lane & 15;   // output col
  float p = 0.f;
#pragma unroll
  for (int i = 0; i < 16; ++i) {
    int k = q * 16 + i;
    p = fmaf(hsh[wib][k], W2[k * NOUT + c], p);
  }
  p += __shfl_xor(p, 16);
  p += __shfl_xor(p, 32);
  if (lane < 16) support2[(size_t)r * NOUT + lane] = p;
}

// ---------------------------------------------------------------------------
// K3: wave per dst row; lane = (edge-slot es 0..3, col c 0..15).
// FIX vs round 10: loop bound padded to n4 = (n+3)&~3 so the trip count is
// uniform across the wave -> no divergent __shfl (bpermute from inactive
// lanes read as 0 and silently DROPPED tail edges when n%4 != 0).
// Padded iterations read lanes in [n, n4) whose myvs = {0,0} -> contribute 0.
// ---------------------------------------------------------------------------
__global__ __launch_bounds__(256) void spmm2_csr_kernel(
    const float* __restrict__ support2, const int2* __restrict__ sorted_vs,
    const int* __restrict__ row_start, const int* __restrict__ counts,
    const float* __restrict__ b2, float* __restrict__ out) {
  int wave = (blockIdx.x * blockDim.x + threadIdx.x) >> 6;
  int lane = threadIdx.x & 63;
  int es = lane >> 4;  // edge slot 0..3
  int c = lane & 15;   // output col
  int r = wave;
  int beg = row_start[r];
  int cnt = counts[r];
  float acc = 0.f;
  for (int b64 = 0; b64 < cnt; b64 += 64) {
    int n = min(64, cnt - b64);
    int n4 = (n + 3) & ~3;  // uniform padded bound (<= 64)
    int2 myvs;
    myvs.x = 0;
    myvs.y = 0;
    if (lane < n) myvs = sorted_vs[beg + b64 + lane];
#pragma unroll 2
    for (int i = es; i < n4; i += 4) {  // same trip count for all lanes
      int sx = __shfl(myvs.x, i);
      float v = __int_as_float(__shfl(myvs.y, i));
      acc = fmaf(v, support2[(size_t)sx * NOUT + c], acc);
    }
  }
  acc += __shfl_xor(acc, 16);
  acc += __shfl_xor(acc, 32);
  if (lane < 16) out[(size_t)r * NOUT + lane] = acc + b2[lane];
}

extern "C" void kernel_launch(void* const* d_in, const int* in_sizes, int n_in,
                              void* d_out, int out_size, void* d_ws,
                              size_t ws_size, hipStream_t stream) {
  const float* emb = (const float*)d_in[0];
  const float* W1 = (const float*)d_in[1];
  const float* b1 = (const float*)d_in[2];
  const float* W2 = (const float*)d_in[3];
  const float* b2 = (const float*)d_in[4];
  const float* edge_val = (const float*)d_in[5];
  const float* mask = (const float*)d_in[6];
  const int* esrc = (const int*)d_in[7];
  const int* edst = (const int*)d_in[8];

  // workspace layout (4-byte units)
  float* ws = (float*)d_ws;
  int2* tmp_vs = (int2*)ws;                           // 1.6M int2 (12.8 MB)
  unsigned short* support1 = (unsigned short*)ws;     // aliases tmp_vs
                                                      //  (written after sort)
  int2* sorted_vs = (int2*)(ws + 6400000);            // 1.6M int2
  float* support2 = ws + 9600000;                     // 1.6M f
  int* scanTmpM = (int*)support2;                     // aliases support2 (dead
                                                      //  before spmm1 writes)
  int* row_start = (int*)(ws + 11200000);             // 100,000 i
  int* counts = row_start + 100000;                   // 100,000 i
  int* histMat = counts + 100000;                     // 152,881 i (becomes mEx)
  int* mBlockSums = histMat + MATN;                   // 1024 i
  int* mBlockOff = mBlockSums + 1024;                 // 1024 i
  float* out = (float*)d_out;

  // CSR build: chunk-histogram -> matrix scan -> ownership scatter -> sort
  histB_kernel<<<NCHUNK, 256, 0, stream>>>(edst, histMat);
  mscan1_kernel<<<MSCAN_NB, 256, 0, stream>>>(histMat, scanTmpM, mBlockSums);
  mscan2_kernel<<<1, 1024, 0, stream>>>(mBlockSums, mBlockOff);
  mscan3_kernel<<<MSCAN_NB, 256, 0, stream>>>(scanTmpM, mBlockOff, histMat);
  scatter2_kernel<<<NCHUNK, 256, 0, stream>>>(esrc, edst, edge_val, histMat,
                                              tmp_vs);
  bucket_sort_kernel<<<NBUCK, 256, 0, stream>>>(tmp_vs, histMat, sorted_vs,
                                                row_start, counts);

  // dense + sparse pipeline (gemm1 after sort: support1 aliases tmp_vs)
  gemm1_kernel<<<(N_NODES + 63) / 64, 256, 0, stream>>>(emb, W1, support1);
  spmm1_fused_kernel<<<N_NODES / 4, 256, 0, stream>>>(
      support1, sorted_vs, row_start, counts, b1, mask, W2, support2);
  spmm2_csr_kernel<<<N_NODES / 4, 256, 0, stream>>>(
      support2, sorted_vs, row_start, counts, b2, out);
}

// Round 12
// 264.845 us; speedup vs baseline: 3.7280x; 1.0167x over previous
//
#include <hip/hip_runtime.h>

#define N_NODES 100000
#define N_EDGES 1600000
#define NFEAT 256
#define NHID 64
#define NOUT 16
#define BSIZE 256            // dst-nodes per bucket
#define NBUCK 391            // ceil(N_NODES/256)
#define CHUNK 4096           // edges per chunk
#define NCHUNK 391           // ceil(N_EDGES/4096)
#define MATN (NBUCK * NCHUNK)
#define MSCAN_NB 598         // ceil(MATN/256)

__device__ __forceinline__ unsigned short f2bf(float f) {
  unsigned u = __float_as_uint(f);
  unsigned r = (u + 0x7FFF + ((u >> 16) & 1)) >> 16;  // RNE
  return (unsigned short)r;
}
__device__ __forceinline__ float bf2f(unsigned short b) {
  return __uint_as_float(((unsigned)b) << 16);
}

// ---------------------------------------------------------------------------
// S1: per-chunk bucket histogram -> histMat[bucket*NCHUNK + chunk]
// ---------------------------------------------------------------------------
__global__ __launch_bounds__(256) void histB_kernel(
    const int* __restrict__ dst, int* __restrict__ histMat) {
  __shared__ int hist[NBUCK];
  int t = threadIdx.x;
  int ch = blockIdx.x;
  if (t < NBUCK) hist[t] = 0;
  if (t + 256 < NBUCK) hist[t + 256] = 0;
  __syncthreads();
  int base = ch * CHUNK;
#pragma unroll
  for (int i = 0; i < CHUNK / 256; ++i) {
    int e = base + i * 256 + t;
    if (e < N_EDGES) atomicAdd(&hist[dst[e] >> 8], 1);
  }
  __syncthreads();
  if (t < NBUCK) histMat[t * NCHUNK + ch] = hist[t];
  if (t + 256 < NBUCK) histMat[(t + 256) * NCHUNK + ch] = hist[t + 256];
}

// ---------------------------------------------------------------------------
// S2a: per-256-block scan of histMat -> exclusive-within-block + blockSums
// ---------------------------------------------------------------------------
__global__ __launch_bounds__(256) void mscan1_kernel(
    const int* __restrict__ histMat, int* __restrict__ scanTmp,
    int* __restrict__ blockSums) {
  __shared__ int s[256];
  int t = threadIdx.x;
  int i = blockIdx.x * 256 + t;
  int v = (i < MATN) ? histMat[i] : 0;
  s[t] = v;
  __syncthreads();
  for (int off = 1; off < 256; off <<= 1) {
    int x = (t >= off) ? s[t - off] : 0;
    __syncthreads();
    s[t] += x;
    __syncthreads();
  }
  if (i < MATN) scanTmp[i] = s[t] - v;  // exclusive within block
  if (t == 255) blockSums[blockIdx.x] = s[255];
}

// ---------------------------------------------------------------------------
// S2b: single-block exclusive scan of MSCAN_NB block sums (<=1024)
// ---------------------------------------------------------------------------
__global__ __launch_bounds__(1024) void mscan2_kernel(
    const int* __restrict__ blockSums, int* __restrict__ blockOff) {
  __shared__ int s[1024];
  int t = threadIdx.x;
  int v = (t < MSCAN_NB) ? blockSums[t] : 0;
  s[t] = v;
  __syncthreads();
  for (int off = 1; off < 1024; off <<= 1) {
    int x = (t >= off) ? s[t - off] : 0;
    __syncthreads();
    s[t] += x;
    __syncthreads();
  }
  if (t < MSCAN_NB) blockOff[t] = s[t] - v;  // exclusive
}

// ---------------------------------------------------------------------------
// S2c: mEx[i] = scanTmp[i] + blockOff[block]   (in-place over histMat)
// ---------------------------------------------------------------------------
__global__ __launch_bounds__(256) void mscan3_kernel(
    const int* __restrict__ scanTmp, const int* __restrict__ blockOff,
    int* __restrict__ mEx) {
  int i = blockIdx.x * 256 + threadIdx.x;
  if (i < MATN) mEx[i] = scanTmp[i] + blockOff[blockIdx.x];
}

// ---------------------------------------------------------------------------
// S3: scatter edges into bucket-grouped tmp_vs. No global atomics: each
// (bucket,chunk) range is exclusively owned by this block (from mEx).
// dlow = dst&255 packed into bits 17..24 of x (src < 2^17).
// ---------------------------------------------------------------------------
__global__ __launch_bounds__(256) void scatter2_kernel(
    const int* __restrict__ src, const int* __restrict__ dst,
    const float* __restrict__ edge_val, const int* __restrict__ mEx,
    int2* __restrict__ tmp_vs) {
  __shared__ int cur[NBUCK];
  int t = threadIdx.x;
  int bid = blockIdx.x;
  // bijective XCD swizzle: q=NCHUNK/8, r=NCHUNK%8
  int xcd = bid & 7;
  int q = NCHUNK >> 3, r = NCHUNK & 7;
  int ch = (xcd < r ? xcd * (q + 1) : r * (q + 1) + (xcd - r) * q) + (bid >> 3);
  if (t < NBUCK) cur[t] = mEx[t * NCHUNK + ch];
  if (t + 256 < NBUCK) cur[t + 256] = mEx[(t + 256) * NCHUNK + ch];
  __syncthreads();
  int base = ch * CHUNK;
#pragma unroll
  for (int i = 0; i < CHUNK / 256; ++i) {
    int e = base + i * 256 + t;
    if (e < N_EDGES) {
      int d = dst[e];
      int p = atomicAdd(&cur[d >> 8], 1);  // LDS atomic
      int2 vs;
      vs.x = src[e] | ((d & 255) << 17);
      vs.y = __float_as_int(edge_val[e]);
      tmp_vs[p] = vs;
    }
  }
}

// ---------------------------------------------------------------------------
// S4: within-bucket counting sort. One block per bucket (256 nodes):
// pass1 counts nodes in LDS, local scan -> row_start/counts written here,
// pass2 scatters into exact CSR slots (~32 KB L2-resident window).
// ---------------------------------------------------------------------------
__global__ __launch_bounds__(256) void bucket_sort_kernel(
    const int2* __restrict__ tmp_vs, const int* __restrict__ mEx,
    int2* __restrict__ sorted_vs, int* __restrict__ row_start,
    int* __restrict__ counts) {
  __shared__ int cnt[256], scn[256], cur[256];
  int b = blockIdx.x;
  int t = threadIdx.x;
  int bstart = mEx[b * NCHUNK];
  int bend = (b + 1 < NBUCK) ? mEx[(b + 1) * NCHUNK] : N_EDGES;
  cnt[t] = 0;
  __syncthreads();
  for (int e = bstart + t; e < bend; e += 256)
    atomicAdd(&cnt[((unsigned)tmp_vs[e].x) >> 17], 1);
  __syncthreads();
  scn[t] = cnt[t];
  __syncthreads();
  for (int off = 1; off < 256; off <<= 1) {
    int x = (t >= off) ? scn[t - off] : 0;
    __syncthreads();
    scn[t] += x;
    __syncthreads();
  }
  int excl = scn[t] - cnt[t];
  cur[t] = bstart + excl;
  int node = (b << 8) + t;
  if (node < N_NODES) {
    row_start[node] = bstart + excl;
    counts[node] = cnt[t];
  }
  __syncthreads();
  for (int e = bstart + t; e < bend; e += 256) {
    int2 vs = tmp_vs[e];
    int dlow = ((unsigned)vs.x) >> 17;
    int p = atomicAdd(&cur[dlow], 1);
    int2 o;
    o.x = vs.x & 0x1FFFF;
    o.y = vs.y;
    sorted_vs[p] = o;
  }
}

// ---------------------------------------------------------------------------
// K1: support1 = bf16(emb @ W1)   [100000,256] @ [256,64]
// Block = 64 rows x 4 waves; wave wq owns col-quarter [wq*16, wq*16+16).
// ---------------------------------------------------------------------------
__global__ __launch_bounds__(256) void gemm1_kernel(
    const float* __restrict__ emb, const float* __restrict__ W1,
    unsigned short* __restrict__ out) {
  int lane = threadIdx.x & 63;
  int wq = __builtin_amdgcn_readfirstlane(threadIdx.x >> 6);
  int row = blockIdx.x * 64 + lane;
  int rclamp = row < N_NODES ? row : (N_NODES - 1);
  const float* er = emb + (size_t)rclamp * NFEAT;
  const float* w1q = W1 + wq * 16;  // scalar base

  float acc[16];
#pragma unroll
  for (int c = 0; c < 16; ++c) acc[c] = 0.f;

  for (int k0 = 0; k0 < NFEAT; k0 += 16) {
    float eb[16];
#pragma unroll
    for (int q = 0; q < 4; ++q)
      *(float4*)(eb + 4 * q) = *(const float4*)(er + k0 + 4 * q);
#pragma unroll
    for (int j = 0; j < 16; ++j) {
      const float* w = w1q + (size_t)(k0 + j) * NHID;  // lane-invariant
#pragma unroll
      for (int c = 0; c < 16; ++c) acc[c] = fmaf(eb[j], w[c], acc[c]);
    }
  }

  if (row < N_NODES) {
    unsigned short* o = out + (size_t)row * NHID + wq * 16;
    ushort4 pk[4];
#pragma unroll
    for (int g = 0; g < 4; ++g) {
      pk[g].x = f2bf(acc[4 * g + 0]);
      pk[g].y = f2bf(acc[4 * g + 1]);
      pk[g].z = f2bf(acc[4 * g + 2]);
      pk[g].w = f2bf(acc[4 * g + 3]);
    }
    *(ushort4*)(o + 0) = pk[0];
    *(ushort4*)(o + 4) = pk[1];
    *(ushort4*)(o + 8) = pk[2];
    *(ushort4*)(o + 12) = pk[3];
  }
}

// ---------------------------------------------------------------------------
// K2 (fused): wave per dst row.
// Edge descriptors fetched 8-at-a-time with wave-UNIFORM indices -> scalar
// s_load batch (all 8 issue immediately, no per-edge dependent chain), then
// 8 independent gathers with wave-uniform guards (j < n). Over-reads past
// the row end hit neighboring rows / ws scratch (readable, never used).
//   acc[lane] = sum_e val_e * bf16 support1[src_e][lane]
//   h = relu(acc + b1) * mask ;  support2 = h @ W2 (LDS + shfl reduce)
// ---------------------------------------------------------------------------
__global__ __launch_bounds__(256) void spmm1_fused_kernel(
    const unsigned short* __restrict__ support1,
    const int2* __restrict__ sorted_vs, const int* __restrict__ row_start,
    const int* __restrict__ counts, const float* __restrict__ b1,
    const float* __restrict__ mask, const float* __restrict__ W2,
    float* __restrict__ support2) {
  int wave = (blockIdx.x * blockDim.x + threadIdx.x) >> 6;
  int lane = threadIdx.x & 63;
  int wib = threadIdx.x >> 6;
  int r = wave;
  int beg = row_start[r];
  int cnt = counts[r];
  float acc = 0.f;
  for (int b8 = 0; b8 < cnt; b8 += 8) {
    int n = min(8, cnt - b8);  // wave-uniform
    int2 ev[8];
#pragma unroll
    for (int j = 0; j < 8; ++j) ev[j] = sorted_vs[beg + b8 + j];
#pragma unroll
    for (int j = 0; j < 8; ++j) {
      if (j < n) {  // uniform guard: tail fmas skipped, loads never issued
        acc = fmaf(__int_as_float(ev[j].y),
                   bf2f(support1[(size_t)ev[j].x * NHID + lane]), acc);
      }
    }
  }
  float h = fmaxf(acc + b1[lane], 0.f) * mask[(size_t)r * NHID + lane];

  __shared__ float hsh[4][NHID];
  hsh[wib][lane] = h;
  __syncthreads();
  int q = lane >> 4;   // 0..3 : k-quarter
  int c = lane & 15;   // output col
  float p = 0.f;
#pragma unroll
  for (int i = 0; i < 16; ++i) {
    int k = q * 16 + i;
    p = fmaf(hsh[wib][k], W2[k * NOUT + c], p);
  }
  p += __shfl_xor(p, 16);
  p += __shfl_xor(p, 32);
  if (lane < 16) support2[(size_t)r * NOUT + lane] = p;
}

// ---------------------------------------------------------------------------
// K3: out[row][c] = sum_e val_e * support2[src_e][c] + b2[c]
// 16 lanes per row, 4 rows per wave (round-8 proven version).
// ---------------------------------------------------------------------------
__global__ __launch_bounds__(256) void spmm2_csr_kernel(
    const float* __restrict__ support2, const int2* __restrict__ sorted_vs,
    const int* __restrict__ row_start, const int* __restrict__ counts,
    const float* __restrict__ b2, float* __restrict__ out) {
  int t = blockIdx.x * blockDim.x + threadIdx.x;
  int r = t >> 4;
  int c = t & 15;
  if (r >= N_NODES) return;
  int beg = row_start[r];
  int end = beg + counts[r];
  float acc = 0.f;
#pragma unroll 4
  for (int e = beg; e < end; ++e) {
    int2 vs = sorted_vs[e];
    acc = fmaf(__int_as_float(vs.y), support2[(size_t)vs.x * NOUT + c], acc);
  }
  out[(size_t)r * NOUT + c] = acc + b2[c];
}

extern "C" void kernel_launch(void* const* d_in, const int* in_sizes, int n_in,
                              void* d_out, int out_size, void* d_ws,
                              size_t ws_size, hipStream_t stream) {
  const float* emb = (const float*)d_in[0];
  const float* W1 = (const float*)d_in[1];
  const float* b1 = (const float*)d_in[2];
  const float* W2 = (const float*)d_in[3];
  const float* b2 = (const float*)d_in[4];
  const float* edge_val = (const float*)d_in[5];
  const float* mask = (const float*)d_in[6];
  const int* esrc = (const int*)d_in[7];
  const int* edst = (const int*)d_in[8];

  // workspace layout (4-byte units)
  float* ws = (float*)d_ws;
  int2* tmp_vs = (int2*)ws;                           // 1.6M int2 (12.8 MB)
  unsigned short* support1 = (unsigned short*)ws;     // aliases tmp_vs
                                                      //  (written after sort)
  int2* sorted_vs = (int2*)(ws + 6400000);            // 1.6M int2
  float* support2 = ws + 9600000;                     // 1.6M f
  int* scanTmpM = (int*)support2;                     // aliases support2 (dead
                                                      //  before spmm1 writes)
  int* row_start = (int*)(ws + 11200000);             // 100,000 i
  int* counts = row_start + 100000;                   // 100,000 i
  int* histMat = counts + 100000;                     // 152,881 i (becomes mEx)
  int* mBlockSums = histMat + MATN;                   // 1024 i
  int* mBlockOff = mBlockSums + 1024;                 // 1024 i
  float* out = (float*)d_out;

  // CSR build: chunk-histogram -> matrix scan -> ownership scatter -> sort
  histB_kernel<<<NCHUNK, 256, 0, stream>>>(edst, histMat);
  mscan1_kernel<<<MSCAN_NB, 256, 0, stream>>>(histMat, scanTmpM, mBlockSums);
  mscan2_kernel<<<1, 1024, 0, stream>>>(mBlockSums, mBlockOff);
  mscan3_kernel<<<MSCAN_NB, 256, 0, stream>>>(scanTmpM, mBlockOff, histMat);
  scatter2_kernel<<<NCHUNK, 256, 0, stream>>>(esrc, edst, edge_val, histMat,
                                              tmp_vs);
  bucket_sort_kernel<<<NBUCK, 256, 0, stream>>>(tmp_vs, histMat, sorted_vs,
                                                row_start, counts);

  // dense + sparse pipeline (gemm1 after sort: support1 aliases tmp_vs)
  gemm1_kernel<<<(N_NODES + 63) / 64, 256, 0, stream>>>(emb, W1, support1);
  spmm1_fused_kernel<<<N_NODES / 4, 256, 0, stream>>>(
      support1, sorted_vs, row_start, counts, b1, mask, W2, support2);
  spmm2_csr_kernel<<<(N_NODES * NOUT + 255) / 256, 256, 0, stream>>>(
      support2, sorted_vs, row_start, counts, b2, out);
}